// Round 1
// baseline (457.965 us; speedup 1.0000x reference)
//
#include <hip/hip_runtime.h>

// Problem constants (from setup_inputs): B=32, K=9, C=3, H=W=256, N_INPUTS=2.
#define BB 32
#define KK 9
#define CC 3
#define HH 256
#define WW 256
#define HW (HH * WW)           // 65536 = 2^16

// d_out layout (floats), in reference return order:
//  o0 pred      [B,3,H,W]   o1 m_mask_f [B,9,H,W]   o2 1-app_f [B,1,H,W]
//  o3 attn      [B,1,H,W]   o4 m_mask_b [B,9,H,W]   o5 1-app_b [B,1,H,W]
//  o6 1-attn    [B,1,H,W]
#define SZ_P ((size_t)BB * CC * HW)
#define SZ_M ((size_t)BB * KK * HW)
#define SZ_S ((size_t)BB * HW)

// Tile geometry: 64x16 output pixels per block, 256 threads (4 px/thread).
#define TX 64
#define TY 16
#define TILES_X (WW / TX)            // 4
#define TILES_Y (HH / TY)            // 16
#define TILES_PER_B (TILES_X * TILES_Y)  // 64

// Fully fused: one pass over gt_f/gt_b serves (a) mask pass-through,
// (b) seg->attn/dis outputs, (c) pred via LDS-staged seg tiles.
// Eliminates 2 D2D memcpys + 2 of the 3 gt streams + the dis/attn HBM
// round trip of the previous 4-dispatch structure.
__global__ __launch_bounds__(256) void fused_binet_kernel(
    const float* __restrict__ im_f, const float* __restrict__ im_b,
    const float* __restrict__ gt_f, const float* __restrict__ gt_b,
    float* __restrict__ out) {
  // seg tiles with halo 1. Row stride 66 floats: lanes read stride-1 ->
  // 2 lanes/bank (free on 32-bank LDS).
  __shared__ float s_sf[TY + 2][TX + 2];
  __shared__ float s_sb[TY + 2][TX + 2];

  int bid = blockIdx.x;
  int b = bid / TILES_PER_B;
  int t = bid % TILES_PER_B;
  int ty0 = (t / TILES_X) * TY;
  int tx0 = (t % TILES_X) * TX;

  const float* gf  = gt_f + (size_t)b * KK * HW;
  const float* gb  = gt_b + (size_t)b * KK * HW;
  // im_input has 6 channels; reference uses the last 3.
  const float* imf = im_f + ((size_t)b * 6 + 3) * HW;
  const float* imb = im_b + ((size_t)b * 6 + 3) * HW;

  int tid = threadIdx.x;

  // ---- Phase 1: seg_f/seg_b over tile + halo-1 -> LDS ----
  // seg[y,x] = sum_k gt[k, y+k/3-1, x+k%3-1]  (zero-padded conv w/ one-hot
  // eye kernel). Halo positions outside the image are never consumed
  // (their mask contribution is zero); store 0 there.
  for (int i = tid; i < (TY + 2) * (TX + 2); i += 256) {
    int ly = i / (TX + 2);
    int lx = i - ly * (TX + 2);
    int y = ty0 + ly - 1;
    int x = tx0 + lx - 1;
    float sf = 0.f, sb = 0.f;
    if (y >= 0 && y < HH && x >= 0 && x < WW) {
#pragma unroll
      for (int k = 0; k < KK; ++k) {
        int yy = y + (k / 3) - 1;
        int xx = x + (k % 3) - 1;
        if (yy >= 0 && yy < HH && xx >= 0 && xx < WW) {
          int off = k * HW + (yy << 8) + xx;
          sf += gf[off];
          sb += gb[off];
        }
      }
    }
    s_sf[ly][lx] = sf;
    s_sb[ly][lx] = sb;
  }
  __syncthreads();

  // ---- Phase 2: outputs ----
  float* o_mf     = out + SZ_P;                          // o1
  float* o_disf   = out + SZ_P + SZ_M;                   // o2
  float* o_attn   = o_disf + SZ_S;                       // o3
  float* o_mb     = o_attn + SZ_S;                       // o4
  float* o_disb   = o_mb + SZ_M;                         // o5
  float* o_1mattn = o_disb + SZ_S;                       // o6

  int lx  = tid & (TX - 1);   // 0..63: full wave reads stride-1 rows
  int ly0 = tid >> 6;         // 0..3

#pragma unroll
  for (int r = 0; r < 4; ++r) {
    int ly = ly0 + r * 4;
    int h = ty0 + ly;
    int w = tx0 + lx;
    int hw = (h << 8) + w;
    size_t sidx = (size_t)b * HW + hw;

    float sf = s_sf[ly + 1][lx + 1];
    float sb = s_sb[ly + 1][lx + 1];
    float dis_f = fmaxf(sf - 1.f, 0.f);
    float app_f = fmaxf(1.f - dis_f, 0.f);
    float dis_b = fmaxf(sb - 1.f, 0.f);
    float app_b = fmaxf(1.f - dis_b, 0.f);
    float sfc = 1.f - fmaxf(1.f - sf, 0.f);
    float sbc = 1.f - fmaxf(1.f - sb, 0.f);
    float attn = (sfc + 1e-5f) / (sfc + sbc + 2e-5f);

    o_disf[sidx]   = 1.f - app_f;
    o_attn[sidx]   = attn;
    o_disb[sidx]   = 1.f - app_b;
    o_1mattn[sidx] = 1.f - attn;

    float pf0 = 0.f, pf1 = 0.f, pf2 = 0.f;
    float pb0 = 0.f, pb1 = 0.f, pb2 = 0.f;
#pragma unroll
    for (int k = 0; k < KK; ++k) {
      // Mask pass-through: same cachelines phase 1 already pulled in.
      size_t moff = (size_t)b * KK * HW + (size_t)k * HW + hw;
      o_mf[moff] = gf[k * HW + hw];
      o_mb[moff] = gb[k * HW + hw];

      int y = h + (k / 3) - 1;
      int x = w + (k % 3) - 1;
      if (y >= 0 && y < HH && x >= 0 && x < WW) {
        int p = (y << 8) + x;
        // appear at neighbor q from LDS seg (no recompute, no HBM trip)
        float sfq = s_sf[ly + (k / 3)][lx + (k % 3)];
        float af = fmaxf(1.f - fmaxf(sfq - 1.f, 0.f), 0.f);
        float cf = af * gf[k * HW + p];
        pf0 = fmaf(cf, imf[p], pf0);
        pf1 = fmaf(cf, imf[HW + p], pf1);
        pf2 = fmaf(cf, imf[2 * HW + p], pf2);
        float sbq = s_sb[ly + (k / 3)][lx + (k % 3)];
        float ab = fmaxf(1.f - fmaxf(sbq - 1.f, 0.f), 0.f);
        float cb = ab * gb[k * HW + p];
        pb0 = fmaf(cb, imb[p], pb0);
        pb1 = fmaf(cb, imb[HW + p], pb1);
        pb2 = fmaf(cb, imb[2 * HW + p], pb2);
      }
    }
    float at2 = 1.f - attn;
    size_t pbase = (size_t)b * CC * HW + hw;
    out[pbase]          = fmaf(attn, pf0, at2 * pb0);
    out[pbase + HW]     = fmaf(attn, pf1, at2 * pb1);
    out[pbase + 2 * HW] = fmaf(attn, pf2, at2 * pb2);
  }
}

extern "C" void kernel_launch(void* const* d_in, const int* in_sizes, int n_in,
                              void* d_out, int out_size, void* d_ws, size_t ws_size,
                              hipStream_t stream) {
  const float* im_f = (const float*)d_in[0];
  const float* im_b = (const float*)d_in[1];
  // d_in[2] = ones (unused — multiplies masks by 1)
  const float* gt_f = (const float*)d_in[3];
  const float* gt_b = (const float*)d_in[4];
  // d_in[5] = m_kernel (one-hot eye, hardcoded as shifts)
  float* out = (float*)d_out;

  dim3 block(256);
  dim3 grid(BB * TILES_PER_B);  // 2048 blocks, one 64x16 tile each

  fused_binet_kernel<<<grid, block, 0, stream>>>(im_f, im_b, gt_f, gt_b, out);
}

// Round 2
// 420.978 us; speedup vs baseline: 1.0879x; 1.0879x over previous
//
#include <hip/hip_runtime.h>

// Problem constants (from setup_inputs): B=32, K=9, C=3, H=W=256, N_INPUTS=2.
#define BB 32
#define KK 9
#define CC 3
#define HH 256
#define WW 256
#define HW (HH * WW)           // 65536 = 2^16

// d_out layout (floats), in reference return order:
//  o0 pred      [B,3,H,W]   o1 m_mask_f [B,9,H,W]   o2 1-app_f [B,1,H,W]
//  o3 attn      [B,1,H,W]   o4 m_mask_b [B,9,H,W]   o5 1-app_b [B,1,H,W]
//  o6 1-attn    [B,1,H,W]
#define SZ_P ((size_t)BB * CC * HW)
#define SZ_M ((size_t)BB * KK * HW)
#define SZ_S ((size_t)BB * HW)

// Tile: 64x16 pixels, 512 threads, 2 px/thread.
// Register-carry design: the 9 shifted gt loads per pixel ARE the seg terms
// AND the pred-product gt operands -> gt streams from HBM once (plus halo),
// eliminating round-1's second 151 MB gt fetch (FETCH was 388 MB, ideal ~200).
#define TX 64
#define TY 16
#define RING ((TY + 2) * (TX + 2) - TY * TX)  // 164 halo-ring pixels

__global__ __launch_bounds__(512) void fused_binet_kernel(
    const float* __restrict__ im_f, const float* __restrict__ im_b,
    const float* __restrict__ gt_f, const float* __restrict__ gt_b,
    float* __restrict__ out) {
  // seg tiles with halo 1; row stride 66 -> stride-1 lane reads, conflict-free.
  __shared__ float s_sf[TY + 2][TX + 2];
  __shared__ float s_sb[TY + 2][TX + 2];

  // XCD swizzle: 2048 blocks = 8 XCDs x 256. Within a chunk, consecutive
  // blocks are vertically adjacent tiles -> shared halo rows hit same-XCD L2.
  int bid = blockIdx.x;
  int actual = ((bid & 7) << 8) | (bid >> 3);
  int b   = actual >> 6;          // 64 tiles per batch image
  int rem = actual & 63;
  int tx0 = (rem >> 4) << 6;      // 4 tiles across
  int ty0 = (rem & 15) << 4;      // 16 tiles down (consecutive in `actual`)

  const float* gf  = gt_f + (size_t)b * KK * HW;
  const float* gb  = gt_b + (size_t)b * KK * HW;
  // im_input has 6 channels; reference uses the last 3.
  const float* imf = im_f + ((size_t)b * 6 + 3) * HW;
  const float* imb = im_b + ((size_t)b * 6 + 3) * HW;

  float* o_mf     = out + SZ_P;                          // o1
  float* o_disf   = out + SZ_P + SZ_M;                   // o2
  float* o_attn   = o_disf + SZ_S;                       // o3
  float* o_mb     = o_attn + SZ_S;                       // o4
  float* o_disb   = o_mb + SZ_M;                         // o5
  float* o_1mattn = o_disb + SZ_S;                       // o6

  int tid = threadIdx.x;
  int lx  = tid & (TX - 1);       // 0..63: full wave reads stride-1 rows
  int ly0 = tid >> 6;             // 0..7

  float rf[2][KK], rb[2][KK];     // carried gt values (static indices only)
  float segf[2], segb[2];

  // ---- Phase A: shifted gt loads -> regs (seg terms == pred operands),
  //      center gt loads (L1 hits) -> mask pass-through stores.
#pragma unroll
  for (int r = 0; r < 2; ++r) {
    int ly = ly0 + r * 8;
    int h  = ty0 + ly;
    int w  = tx0 + lx;
    int hw = (h << 8) | w;
    float sf = 0.f, sb = 0.f;
#pragma unroll
    for (int k = 0; k < KK; ++k) {
      int y = h + (k / 3) - 1;
      int x = w + (k % 3) - 1;
      float vf = 0.f, vb = 0.f;
      if ((unsigned)y < HH && (unsigned)x < WW) {
        int p = k * HW + (y << 8) + x;
        vf = gf[p];
        vb = gb[p];
      }
      rf[r][k] = vf;
      rb[r][k] = vb;
      sf += vf;
      sb += vb;
      size_t moff = (size_t)b * KK * HW + (size_t)k * HW + hw;
      o_mf[moff] = gf[k * HW + hw];   // same cachelines as shifted loads
      o_mb[moff] = gb[k * HW + hw];
    }
    segf[r] = sf;
    segb[r] = sb;
    s_sf[ly + 1][lx + 1] = sf;
    s_sb[ly + 1][lx + 1] = sb;
  }

  // ---- Halo ring seg: 164 pixels, 9-point gather (mostly L1/L2 hits).
  if (tid < RING) {
    int ly, lxr;
    if (tid < TX + 2) { ly = 0; lxr = tid; }
    else if (tid < 2 * (TX + 2)) { ly = TY + 1; lxr = tid - (TX + 2); }
    else {
      int j = tid - 2 * (TX + 2);        // 0..31
      ly  = 1 + (j & 15);
      lxr = (j >> 4) ? (TX + 1) : 0;
    }
    int yq = ty0 + ly - 1;
    int xq = tx0 + lxr - 1;
    float sf = 0.f, sb = 0.f;
    if ((unsigned)yq < HH && (unsigned)xq < WW) {
#pragma unroll
      for (int k = 0; k < KK; ++k) {
        int y = yq + (k / 3) - 1;
        int x = xq + (k % 3) - 1;
        if ((unsigned)y < HH && (unsigned)x < WW) {
          int p = k * HW + (y << 8) + x;
          sf += gf[p];
          sb += gb[p];
        }
      }
    }
    s_sf[ly][lxr] = sf;   // out-of-image ring never consumed (bounds guard)
    s_sb[ly][lxr] = sb;
  }
  __syncthreads();

  // ---- Phase B+C: scalar outputs + pred from registers/LDS/im.
#pragma unroll
  for (int r = 0; r < 2; ++r) {
    int ly = ly0 + r * 8;
    int h  = ty0 + ly;
    int w  = tx0 + lx;
    int hw = (h << 8) | w;
    size_t sidx = (size_t)b * HW + hw;

    float sf = segf[r];
    float sb = segb[r];
    float dis_f = fmaxf(sf - 1.f, 0.f);
    float app_f = fmaxf(1.f - dis_f, 0.f);
    float dis_b = fmaxf(sb - 1.f, 0.f);
    float app_b = fmaxf(1.f - dis_b, 0.f);
    float sfc = 1.f - fmaxf(1.f - sf, 0.f);
    float sbc = 1.f - fmaxf(1.f - sb, 0.f);
    float attn = (sfc + 1e-5f) / (sfc + sbc + 2e-5f);

    o_disf[sidx]   = 1.f - app_f;
    o_attn[sidx]   = attn;
    o_disb[sidx]   = 1.f - app_b;
    o_1mattn[sidx] = 1.f - attn;

    float pf0 = 0.f, pf1 = 0.f, pf2 = 0.f;
    float pb0 = 0.f, pb1 = 0.f, pb2 = 0.f;
#pragma unroll
    for (int k = 0; k < KK; ++k) {
      int dy = k / 3, dx = k % 3;
      int y = h + dy - 1;
      int x = w + dx - 1;
      if ((unsigned)y < HH && (unsigned)x < WW) {
        int p = (y << 8) + x;
        float sfq = s_sf[ly + dy][lx + dx];
        float af  = fmaxf(1.f - fmaxf(sfq - 1.f, 0.f), 0.f);
        float cf  = af * rf[r][k];              // gt from registers
        pf0 = fmaf(cf, imf[p], pf0);
        pf1 = fmaf(cf, imf[HW + p], pf1);
        pf2 = fmaf(cf, imf[2 * HW + p], pf2);
        float sbq = s_sb[ly + dy][lx + dx];
        float ab  = fmaxf(1.f - fmaxf(sbq - 1.f, 0.f), 0.f);
        float cb  = ab * rb[r][k];
        pb0 = fmaf(cb, imb[p], pb0);
        pb1 = fmaf(cb, imb[HW + p], pb1);
        pb2 = fmaf(cb, imb[2 * HW + p], pb2);
      }
    }
    float at2 = 1.f - attn;
    size_t pbase = (size_t)b * CC * HW + hw;
    out[pbase]          = fmaf(attn, pf0, at2 * pb0);
    out[pbase + HW]     = fmaf(attn, pf1, at2 * pb1);
    out[pbase + 2 * HW] = fmaf(attn, pf2, at2 * pb2);
  }
}

extern "C" void kernel_launch(void* const* d_in, const int* in_sizes, int n_in,
                              void* d_out, int out_size, void* d_ws, size_t ws_size,
                              hipStream_t stream) {
  const float* im_f = (const float*)d_in[0];
  const float* im_b = (const float*)d_in[1];
  // d_in[2] = ones (unused — multiplies masks by 1)
  const float* gt_f = (const float*)d_in[3];
  const float* gt_b = (const float*)d_in[4];
  // d_in[5] = m_kernel (one-hot eye, hardcoded as shifts)
  float* out = (float*)d_out;

  dim3 block(512);
  dim3 grid(BB * 64);   // 2048 tiles of 64x16

  fused_binet_kernel<<<grid, block, 0, stream>>>(im_f, im_b, gt_f, gt_b, out);
}

// Round 3
// 403.886 us; speedup vs baseline: 1.1339x; 1.0423x over previous
//
#include <hip/hip_runtime.h>

// Problem constants (from setup_inputs): B=32, K=9, C=3, H=W=256, N_INPUTS=2.
#define BB 32
#define KK 9
#define CC 3
#define HH 256
#define WW 256
#define HW (HH * WW)           // 65536 = 2^16

// d_out layout (floats), in reference return order:
//  o0 pred      [B,3,H,W]   o1 m_mask_f [B,9,H,W]   o2 1-app_f [B,1,H,W]
//  o3 attn      [B,1,H,W]   o4 m_mask_b [B,9,H,W]   o5 1-app_b [B,1,H,W]
//  o6 1-attn    [B,1,H,W]
#define SZ_P ((size_t)BB * CC * HW)
#define SZ_M ((size_t)BB * KK * HW)
#define SZ_S ((size_t)BB * HW)

typedef float f4 __attribute__((ext_vector_type(4)));

__device__ __forceinline__ f4 ld4(const float* p) { return *(const f4*)p; }
__device__ __forceinline__ void st4(float* p, f4 v) { *(f4*)p = v; }
// NT stores for outputs never re-read: keep gt/im resident in L2/L3 for kernel B.
__device__ __forceinline__ void ntst4(float* p, f4 v) {
  __builtin_nontemporal_store(v, (f4*)p);
}
__device__ __forceinline__ f4 vmax(f4 a, f4 b) {
  return __builtin_elementwise_max(a, b);
}
// Shifted 4-wide window from {left, v, right}: dx=0 -> x-1, dx=1 -> x, dx=2 -> x+1.
__device__ __forceinline__ f4 win(f4 v, float l, float r, int dx) {
  if (dx == 0) return (f4){l, v.x, v.y, v.z};
  if (dx == 2) return (f4){v.y, v.z, v.w, r};
  return v;
}

// Geometry: thread = one aligned float4 (4 px). Wave (64 lanes) = one full
// 256-px image row, so +-1 column shifts are wave shuffles of edge
// components -- all global loads stay 16B-aligned and independent.
// Block = 256 threads = 4 rows. Grid = 32 images x 64 row-quads = 2048.
__device__ __forceinline__ void decode(int bid, int tid, int& b, int& y,
                                       int& lane, int& x0) {
  // XCD swizzle: bid%8 = XCD -> contiguous 256-block chunk (4 images/XCD).
  int actual = ((bid & 7) << 8) | (bid >> 3);
  b = actual >> 6;
  int q = actual & 63;
  lane = tid & 63;
  y = (q << 2) + (tid >> 6);
  x0 = lane << 2;
}

__global__ __launch_bounds__(256) void seg_mask_kernel(
    const float* __restrict__ gt_f, const float* __restrict__ gt_b,
    float* __restrict__ out) {
  int b, y, lane, x0;
  decode(blockIdx.x, threadIdx.x, b, y, lane, x0);
  size_t hw = ((size_t)y << 8) + x0;

  const float* gf = gt_f + (size_t)b * KK * HW;
  const float* gb = gt_b + (size_t)b * KK * HW;

  float* o_mf     = out + SZ_P;                          // o1
  float* o_disf   = out + SZ_P + SZ_M;                   // o2
  float* o_attn   = o_disf + SZ_S;                       // o3 (re-read by B)
  float* o_mb     = o_attn + SZ_S;                       // o4
  float* o_disb   = o_mb + SZ_M;                         // o5 (re-read by B)
  float* o_1mattn = o_disb + SZ_S;                       // o6

  f4 segf = {0.f, 0.f, 0.f, 0.f};
  f4 segb = {0.f, 0.f, 0.f, 0.f};

#pragma unroll
  for (int k = 0; k < KK; ++k) {
    const int dy = k / 3, dx = k % 3;
    int yr = y + dy - 1;
    bool rowok = (unsigned)yr < HH;        // wave-uniform branch
    f4 vf = {0.f, 0.f, 0.f, 0.f}, vb = {0.f, 0.f, 0.f, 0.f};
    if (rowok) {
      size_t off = (size_t)k * HW + ((size_t)yr << 8) + x0;
      vf = ld4(gf + off);
      vb = ld4(gb + off);
    }
    f4 wf, wb;
    if (dx == 1) {
      wf = vf; wb = vb;
    } else if (dx == 0) {
      float lf = __shfl_up(vf.w, 1), lb = __shfl_up(vb.w, 1);
      if (lane == 0) { lf = 0.f; lb = 0.f; }   // image left edge: zero-pad
      wf = (f4){lf, vf.x, vf.y, vf.z};
      wb = (f4){lb, vb.x, vb.y, vb.z};
    } else {
      float rf = __shfl_down(vf.x, 1), rb = __shfl_down(vb.x, 1);
      if (lane == 63) { rf = 0.f; rb = 0.f; }  // image right edge
      wf = (f4){vf.y, vf.z, vf.w, rf};
      wb = (f4){vb.y, vb.z, vb.w, rb};
    }
    segf += wf;
    segb += wb;

    // Mask pass-through: dy==1 planes already loaded the center row.
    f4 cf = vf, cb = vb;
    if (dy != 1) {
      cf = ld4(gf + (size_t)k * HW + hw);
      cb = ld4(gb + (size_t)k * HW + hw);
    }
    size_t moff = (size_t)b * KK * HW + (size_t)k * HW + hw;
    ntst4(o_mf + moff, cf);
    ntst4(o_mb + moff, cb);
  }

  f4 one = {1.f, 1.f, 1.f, 1.f}, zero = {0.f, 0.f, 0.f, 0.f};
  f4 disf = vmax(segf - one, zero);
  f4 appf = vmax(one - disf, zero);
  f4 disb = vmax(segb - one, zero);
  f4 appb = vmax(one - disb, zero);
  f4 sfc = one - vmax(one - segf, zero);
  f4 sbc = one - vmax(one - segb, zero);
  f4 attn = (sfc + 1e-5f) / (sfc + sbc + 2e-5f);

  size_t sidx = (size_t)b * HW + hw;
  st4(o_disf + sidx, one - appf);     // normal store: B reads these
  st4(o_attn + sidx, attn);           // normal store: B reads
  st4(o_disb + sidx, one - appb);
  ntst4(o_1mattn + sidx, one - attn);
}

__global__ __launch_bounds__(256) void pred_kernel(
    const float* __restrict__ im_f, const float* __restrict__ im_b,
    const float* __restrict__ gt_f, const float* __restrict__ gt_b,
    float* __restrict__ out) {
  int b, y, lane, x0;
  decode(blockIdx.x, threadIdx.x, b, y, lane, x0);
  size_t hw = ((size_t)y << 8) + x0;

  const float* gf  = gt_f + (size_t)b * KK * HW;
  const float* gb  = gt_b + (size_t)b * KK * HW;
  // im_input has 6 channels; reference uses the last 3.
  const float* imf = im_f + ((size_t)b * 6 + 3) * HW;
  const float* imb = im_b + ((size_t)b * 6 + 3) * HW;
  const float* dfp = out + SZ_P + SZ_M + (size_t)b * HW;               // o2
  const float* atp = out + SZ_P + SZ_M + SZ_S + (size_t)b * HW;        // o3
  const float* dbp = out + SZ_P + 2 * SZ_M + 2 * SZ_S + (size_t)b * HW;// o5

  f4 z = {0.f, 0.f, 0.f, 0.f};
  f4 pf0 = z, pf1 = z, pf2 = z, pb0 = z, pb1 = z, pb2 = z;

#pragma unroll
  for (int dy = 0; dy < 3; ++dy) {
    int yr = y + dy - 1;
    bool rowok = (unsigned)yr < HH;        // wave-uniform
    size_t rbase = ((size_t)yr << 8) + x0;

    f4 dfv = z, dbv = z;
    f4 if0 = z, if1 = z, if2 = z, ib0 = z, ib1 = z, ib2 = z;
    if (rowok) {
      dfv = ld4(dfp + rbase);
      dbv = ld4(dbp + rbase);
      if0 = ld4(imf + rbase);
      if1 = ld4(imf + HW + rbase);
      if2 = ld4(imf + 2 * HW + rbase);
      ib0 = ld4(imb + rbase);
      ib1 = ld4(imb + HW + rbase);
      ib2 = ld4(imb + 2 * HW + rbase);
    }
    // appear = 1 - (1-appear) output. Edge/OOB positions end up multiplied
    // by a zeroed gt window, so unguarded shuffle edges are harmless.
    f4 aff = 1.f - dfv;
    f4 afb = 1.f - dbv;
    float affl = __shfl_up(aff.w, 1),  affr = __shfl_down(aff.x, 1);
    float afbl = __shfl_up(afb.w, 1),  afbr = __shfl_down(afb.x, 1);
    float if0l = __shfl_up(if0.w, 1),  if0r = __shfl_down(if0.x, 1);
    float if1l = __shfl_up(if1.w, 1),  if1r = __shfl_down(if1.x, 1);
    float if2l = __shfl_up(if2.w, 1),  if2r = __shfl_down(if2.x, 1);
    float ib0l = __shfl_up(ib0.w, 1),  ib0r = __shfl_down(ib0.x, 1);
    float ib1l = __shfl_up(ib1.w, 1),  ib1r = __shfl_down(ib1.x, 1);
    float ib2l = __shfl_up(ib2.w, 1),  ib2r = __shfl_down(ib2.x, 1);

#pragma unroll
    for (int dx = 0; dx < 3; ++dx) {
      const int k = 3 * dy + dx;
      f4 gfv = z, gbv = z;
      if (rowok) {
        gfv = ld4(gf + (size_t)k * HW + rbase);
        gbv = ld4(gb + (size_t)k * HW + rbase);
      }
      float gfl = 0.f, gfr = 0.f, gbl = 0.f, gbr = 0.f;
      if (dx == 0) {
        gfl = __shfl_up(gfv.w, 1); gbl = __shfl_up(gbv.w, 1);
        if (lane == 0) { gfl = 0.f; gbl = 0.f; }   // zero-pad: kills edge terms
      } else if (dx == 2) {
        gfr = __shfl_down(gfv.x, 1); gbr = __shfl_down(gbv.x, 1);
        if (lane == 63) { gfr = 0.f; gbr = 0.f; }
      }
      f4 cf = win(aff, affl, affr, dx) * win(gfv, gfl, gfr, dx);
      f4 cb = win(afb, afbl, afbr, dx) * win(gbv, gbl, gbr, dx);
      pf0 += cf * win(if0, if0l, if0r, dx);
      pf1 += cf * win(if1, if1l, if1r, dx);
      pf2 += cf * win(if2, if2l, if2r, dx);
      pb0 += cb * win(ib0, ib0l, ib0r, dx);
      pb1 += cb * win(ib1, ib1l, ib1r, dx);
      pb2 += cb * win(ib2, ib2l, ib2r, dx);
    }
  }

  f4 attn = ld4(atp + hw);
  f4 at2 = 1.f - attn;
  size_t pbase = (size_t)b * CC * HW + hw;
  ntst4(out + pbase,          attn * pf0 + at2 * pb0);
  ntst4(out + pbase + HW,     attn * pf1 + at2 * pb1);
  ntst4(out + pbase + 2 * HW, attn * pf2 + at2 * pb2);
}

extern "C" void kernel_launch(void* const* d_in, const int* in_sizes, int n_in,
                              void* d_out, int out_size, void* d_ws, size_t ws_size,
                              hipStream_t stream) {
  const float* im_f = (const float*)d_in[0];
  const float* im_b = (const float*)d_in[1];
  // d_in[2] = ones (unused — multiplies masks by 1)
  const float* gt_f = (const float*)d_in[3];
  const float* gt_b = (const float*)d_in[4];
  // d_in[5] = m_kernel (one-hot eye, hardcoded as shifts)
  float* out = (float*)d_out;

  dim3 block(256);
  dim3 grid(BB * 64);   // 2048 blocks: 4 image rows each

  seg_mask_kernel<<<grid, block, 0, stream>>>(gt_f, gt_b, out);
  pred_kernel<<<grid, block, 0, stream>>>(im_f, im_b, gt_f, gt_b, out);
}

// Round 4
// 390.987 us; speedup vs baseline: 1.1713x; 1.0330x over previous
//
#include <hip/hip_runtime.h>

// Problem constants (from setup_inputs): B=32, K=9, C=3, H=W=256, N_INPUTS=2.
#define BB 32
#define KK 9
#define CC 3
#define HH 256
#define WW 256
#define HW (HH * WW)           // 65536 = 2^16

// d_out layout (floats), in reference return order:
//  o0 pred      [B,3,H,W]   o1 m_mask_f [B,9,H,W]   o2 1-app_f [B,1,H,W]
//  o3 attn      [B,1,H,W]   o4 m_mask_b [B,9,H,W]   o5 1-app_b [B,1,H,W]
//  o6 1-attn    [B,1,H,W]
#define SZ_P ((size_t)BB * CC * HW)
#define SZ_M ((size_t)BB * KK * HW)
#define SZ_S ((size_t)BB * HW)

typedef float f4 __attribute__((ext_vector_type(4)));

__device__ __forceinline__ f4 ld4(const float* p) { return *(const f4*)p; }
__device__ __forceinline__ void ntst4(float* p, f4 v) {
  __builtin_nontemporal_store(v, (f4*)p);   // outputs are never re-read
}
__device__ __forceinline__ f4 vmax4(f4 a, f4 b) {
  return __builtin_elementwise_max(a, b);
}
// appear = relu(1 - relu(seg - 1))
__device__ __forceinline__ f4 app4(f4 s) {
  f4 one = {1.f, 1.f, 1.f, 1.f}, z = {0.f, 0.f, 0.f, 0.f};
  return vmax4(one - vmax4(s - one, z), z);
}
__device__ __forceinline__ float app1(float s) {
  return fmaxf(1.f - fmaxf(s - 1.f, 0.f), 0.f);
}
// Align a loaded f4 row-window to tap dx (0:x-1, 1:x, 2:x+1) via wave shuffle.
// Lane 0 / lane 63 image edges are zero-padded (conv zero padding).
__device__ __forceinline__ f4 shiftwin(f4 v, int dx, int lane) {
  if (dx == 0) {
    float l = __shfl_up(v.w, 1);
    if (lane == 0) l = 0.f;
    return (f4){l, v.x, v.y, v.z};
  } else if (dx == 2) {
    float r = __shfl_down(v.x, 1);
    if (lane == 63) r = 0.f;
    return (f4){v.y, v.z, v.w, r};
  }
  return v;
}

// One direction (F or B): stencil-load gt once (windows kept in registers =
// seg terms AND pred operands), mask pass-through, seg -> LDS (+2 halo rows),
// then pred accumulation using appear from LDS seg.
__device__ __forceinline__ void run_pass(
    const float* __restrict__ g,   // gt base for this image [K][H][W]
    const float* __restrict__ im,  // im last-3-channel base [3][H][W]
    float* __restrict__ o_m,       // mask pass-through out for this image
    float (*s_seg)[WW],            // [10][256] seg tile, rows y0-1..y0+8
    int w, int lane, int x0, int y0, int y, size_t hw,
    f4& seg_out, f4& p0, f4& p1, f4& p2) {
  const f4 z = {0.f, 0.f, 0.f, 0.f};
  f4 r[KK];
  f4 seg = z;
#pragma unroll
  for (int k = 0; k < KK; ++k) {
    const int dy = k / 3, dx = k % 3;
    int yr = y + dy - 1;
    f4 v = z;
    if ((unsigned)yr < HH)                       // wave-uniform
      v = ld4(g + (size_t)k * HW + ((size_t)yr << 8) + x0);
    f4 wv = shiftwin(v, dx, lane);
    r[k] = wv;                                    // carried to pred phase
    seg += wv;
    // pass-through: center row. dy==1 planes already have it; others L1-hot
    // (loaded as a neighbor wave's stencil row).
    f4 c = (dy == 1) ? v : ld4(g + (size_t)k * HW + hw);
    ntst4(o_m + (size_t)k * HW + hw, c);
  }
  *(f4*)&s_seg[w + 1][x0] = seg;

  // Halo rows y0-1 (wave 0) and y0+8 (wave 1): OOB rows produce seg=0,
  // which is never consumed (zero gt window kills those products).
  if (w < 2) {
    int lr = (w == 0) ? 0 : 9;
    int yh = (w == 0) ? y0 - 1 : y0 + 8;
    f4 s = z;
#pragma unroll
    for (int k = 0; k < KK; ++k) {
      const int dy = k / 3, dx = k % 3;
      int yr = yh + dy - 1;
      f4 v = z;
      if ((unsigned)yr < HH)
        v = ld4(g + (size_t)k * HW + ((size_t)yr << 8) + x0);
      s += shiftwin(v, dx, lane);
    }
    *(f4*)&s_seg[lr][x0] = s;
  }
  __syncthreads();

  p0 = z; p1 = z; p2 = z;
#pragma unroll
  for (int dy = 0; dy < 3; ++dy) {
    const float* srow = s_seg[w + dy];           // row y+dy-1
    f4 sc = *(const f4*)&srow[x0];
    // x0-1 / x0+4 neighbors; clamped at image edges where the product is
    // zero anyway (edge-zeroed gt window).
    float sl = srow[(x0 == 0) ? 0 : (x0 - 1)];
    float sr = srow[(x0 == WW - 4) ? (WW - 1) : (x0 + 4)];
    f4 ac = app4(sc);
    float al = app1(sl), ar = app1(sr);

    int yr = y + dy - 1;
    f4 i0 = z, i1 = z, i2 = z;
    if ((unsigned)yr < HH) {
      size_t rb = ((size_t)yr << 8) + x0;
      i0 = ld4(im + rb);
      i1 = ld4(im + HW + rb);
      i2 = ld4(im + 2 * HW + rb);
    }
    float i0l = __shfl_up(i0.w, 1), i0r = __shfl_down(i0.x, 1);
    float i1l = __shfl_up(i1.w, 1), i1r = __shfl_down(i1.x, 1);
    float i2l = __shfl_up(i2.w, 1), i2r = __shfl_down(i2.x, 1);
#pragma unroll
    for (int dx = 0; dx < 3; ++dx) {
      const int k = 3 * dy + dx;
      f4 aw = (dx == 0) ? (f4){al, ac.x, ac.y, ac.z}
            : (dx == 2) ? (f4){ac.y, ac.z, ac.w, ar} : ac;
      f4 c = aw * r[k];
      f4 w0 = (dx == 0) ? (f4){i0l, i0.x, i0.y, i0.z}
            : (dx == 2) ? (f4){i0.y, i0.z, i0.w, i0r} : i0;
      f4 w1 = (dx == 0) ? (f4){i1l, i1.x, i1.y, i1.z}
            : (dx == 2) ? (f4){i1.y, i1.z, i1.w, i1r} : i1;
      f4 w2 = (dx == 0) ? (f4){i2l, i2.x, i2.y, i2.z}
            : (dx == 2) ? (f4){i2.y, i2.z, i2.w, i2r} : i2;
      p0 += c * w0;
      p1 += c * w1;
      p2 += c * w2;
    }
  }
  __syncthreads();   // protect LDS before next pass overwrites
  seg_out = seg;
}

// Block = 512 threads = 8 waves; wave = one full 256-px image row (lane =
// aligned float4). 8 rows per block, 32 row-groups x 32 images = 1024 blocks.
__global__ __launch_bounds__(512) void fused_binet_kernel(
    const float* __restrict__ im_f, const float* __restrict__ im_b,
    const float* __restrict__ gt_f, const float* __restrict__ gt_b,
    float* __restrict__ out) {
  __shared__ float s_seg[10][WW];   // 10 KB

  // XCD swizzle: 1024 blocks = 8 XCDs x 128; consecutive chunk entries are
  // vertically adjacent row-groups -> shared halo rows hit same-XCD L2.
  int bid = blockIdx.x;
  int actual = ((bid & 7) << 7) | (bid >> 3);
  int b  = actual >> 5;
  int y0 = (actual & 31) << 3;

  int tid  = threadIdx.x;
  int w    = tid >> 6;        // wave index = row within group
  int lane = tid & 63;
  int x0   = lane << 2;
  int y    = y0 + w;
  size_t hw = ((size_t)y << 8) + x0;

  const float* gf  = gt_f + (size_t)b * KK * HW;
  const float* gb  = gt_b + (size_t)b * KK * HW;
  // im_input has 6 channels; reference uses the last 3.
  const float* imf = im_f + ((size_t)b * 6 + 3) * HW;
  const float* imb = im_b + ((size_t)b * 6 + 3) * HW;

  float* o_mf     = out + SZ_P + (size_t)b * KK * HW;          // o1
  float* o_disf   = out + SZ_P + SZ_M;                         // o2
  float* o_attn   = o_disf + SZ_S;                             // o3
  float* o_mb     = o_attn + SZ_S + (size_t)b * KK * HW;       // o4
  float* o_disb   = o_attn + SZ_S + SZ_M;                      // o5
  float* o_1mattn = o_disb + SZ_S;                             // o6

  f4 segf, segb, pf0, pf1, pf2, pb0, pb1, pb2;
  run_pass(gf, imf, o_mf, s_seg, w, lane, x0, y0, y, hw, segf, pf0, pf1, pf2);
  run_pass(gb, imb, o_mb, s_seg, w, lane, x0, y0, y, hw, segb, pb0, pb1, pb2);

  f4 one = {1.f, 1.f, 1.f, 1.f}, z = {0.f, 0.f, 0.f, 0.f};
  f4 appf = app4(segf);
  f4 appb = app4(segb);
  f4 sfc = one - vmax4(one - segf, z);
  f4 sbc = one - vmax4(one - segb, z);
  f4 attn = (sfc + 1e-5f) / (sfc + sbc + 2e-5f);
  f4 at2 = one - attn;

  size_t sidx = (size_t)b * HW + hw;
  ntst4(o_disf + sidx, one - appf);
  ntst4(o_attn + sidx, attn);
  ntst4(o_disb + sidx, one - appb);
  ntst4(o_1mattn + sidx, one - attn);

  size_t pbase = (size_t)b * CC * HW + hw;
  ntst4(out + pbase,          attn * pf0 + at2 * pb0);
  ntst4(out + pbase + HW,     attn * pf1 + at2 * pb1);
  ntst4(out + pbase + 2 * HW, attn * pf2 + at2 * pb2);
}

extern "C" void kernel_launch(void* const* d_in, const int* in_sizes, int n_in,
                              void* d_out, int out_size, void* d_ws, size_t ws_size,
                              hipStream_t stream) {
  const float* im_f = (const float*)d_in[0];
  const float* im_b = (const float*)d_in[1];
  // d_in[2] = ones (unused — multiplies masks by 1)
  const float* gt_f = (const float*)d_in[3];
  const float* gt_b = (const float*)d_in[4];
  // d_in[5] = m_kernel (one-hot eye, hardcoded as shifts)
  float* out = (float*)d_out;

  dim3 block(512);
  dim3 grid(BB * 32);   // 1024 blocks: 8 image rows each

  fused_binet_kernel<<<grid, block, 0, stream>>>(im_f, im_b, gt_f, gt_b, out);
}